// Round 1
// baseline (625.489 us; speedup 1.0000x reference)
//
#include <hip/hip_runtime.h>

#define NEG_SLOPE_F 0.2f

__device__ __forceinline__ float lrelu(float v) { return v > 0.0f ? v : NEG_SLOPE_F * v; }

// ---------------- CSR construction ----------------
__global__ void hist_kernel(const int* __restrict__ dst, int* __restrict__ cnt, int E) {
  for (int i = blockIdx.x * blockDim.x + threadIdx.x; i < E; i += gridDim.x * blockDim.x)
    atomicAdd(&cnt[dst[i]], 1);
}

__global__ void scan_kernel(const int* __restrict__ cnt, int* __restrict__ offs,
                            int* __restrict__ cur, int Nn) {
  __shared__ int part[256];
  __shared__ int base[256];
  int tid = threadIdx.x;
  int per = (Nn + 255) / 256;
  int b = tid * per;
  int e = min(b + per, Nn);
  int s = 0;
  for (int i = b; i < e; ++i) s += cnt[i];
  part[tid] = s;
  __syncthreads();
  if (tid == 0) {
    int run = 0;
    for (int i = 0; i < 256; ++i) { base[i] = run; run += part[i]; }
    offs[Nn] = run;
  }
  __syncthreads();
  int run = base[tid];
  for (int i = b; i < e; ++i) { offs[i] = run; cur[i] = run; run += cnt[i]; }
}

__global__ void scatter_kernel(const int* __restrict__ src, const int* __restrict__ dst,
                               int* __restrict__ cur, int* __restrict__ csr, int E) {
  for (int i = blockIdx.x * blockDim.x + threadIdx.x; i < E; i += gridDim.x * blockDim.x) {
    int p = atomicAdd(&cur[dst[i]], 1);
    csr[p] = src[i];
  }
}

// ---------------- fp32 GEMM: C[M,Nc] = A[M,K] * B[K,Nc] ----------------
// Nc % 64 == 0, K % 16 == 0. 64x64 tile, 256 threads, 4x4 per thread.
__global__ __launch_bounds__(256) void gemm_f32(const float* __restrict__ A,
                                                const float* __restrict__ B,
                                                float* __restrict__ C,
                                                int M, int Nc, int K) {
  __shared__ float As[16][64];  // [k][m]
  __shared__ float Bs[16][64];  // [k][n]
  const int tid = threadIdx.x;
  const int bm = blockIdx.y * 64, bn = blockIdx.x * 64;
  const int ty = tid >> 4, tx = tid & 15;
  const int arow = tid >> 2, acol = (tid & 3) * 4;
  const int brow = tid >> 4, bcol = (tid & 15) * 4;
  const int gr = bm + arow;
  const bool avalid = gr < M;
  float acc[4][4] = {};
  for (int k0 = 0; k0 < K; k0 += 16) {
    float4 av = avalid ? *(const float4*)(A + (size_t)gr * K + k0 + acol)
                       : make_float4(0.f, 0.f, 0.f, 0.f);
    float4 bv = *(const float4*)(B + (size_t)(k0 + brow) * Nc + bn + bcol);
    __syncthreads();
    As[acol + 0][arow] = av.x;
    As[acol + 1][arow] = av.y;
    As[acol + 2][arow] = av.z;
    As[acol + 3][arow] = av.w;
    *(float4*)&Bs[brow][bcol] = bv;
    __syncthreads();
#pragma unroll
    for (int k = 0; k < 16; ++k) {
      float a0 = As[k][ty * 4 + 0], a1 = As[k][ty * 4 + 1];
      float a2 = As[k][ty * 4 + 2], a3 = As[k][ty * 4 + 3];
      float b0 = Bs[k][tx * 4 + 0], b1 = Bs[k][tx * 4 + 1];
      float b2 = Bs[k][tx * 4 + 2], b3 = Bs[k][tx * 4 + 3];
      acc[0][0] += a0 * b0; acc[0][1] += a0 * b1; acc[0][2] += a0 * b2; acc[0][3] += a0 * b3;
      acc[1][0] += a1 * b0; acc[1][1] += a1 * b1; acc[1][2] += a1 * b2; acc[1][3] += a1 * b3;
      acc[2][0] += a2 * b0; acc[2][1] += a2 * b1; acc[2][2] += a2 * b2; acc[2][3] += a2 * b3;
      acc[3][0] += a3 * b0; acc[3][1] += a3 * b1; acc[3][2] += a3 * b2; acc[3][3] += a3 * b3;
    }
  }
#pragma unroll
  for (int i = 0; i < 4; ++i) {
    int r = bm + ty * 4 + i;
    if (r < M) {
      float4 v = make_float4(acc[i][0], acc[i][1], acc[i][2], acc[i][3]);
      *(float4*)(C + (size_t)r * Nc + bn + tx * 4) = v;
    }
  }
}

// ---------------- per-node attention logits ----------------
// al_s[n][h] = sum_d h[n,h,d]*a_src[h,d]; al_d likewise. One wave per node.
template <int D, int VEC>
__global__ void compute_al(const float* __restrict__ h, const float* __restrict__ a_src,
                           const float* __restrict__ a_dst, float* __restrict__ al_s,
                           float* __restrict__ al_d, int Nn) {
  int node = blockIdx.x * (blockDim.x >> 6) + (threadIdx.x >> 6);
  if (node >= Nn) return;
  int lane = threadIdx.x & 63;
  int head = lane >> 4;
  const float* row = h + (size_t)node * (4 * D) + lane * VEC;
  const float* asrc = a_src + head * D + (lane & 15) * VEC;
  const float* adst = a_dst + head * D + (lane & 15) * VEC;
  float ps = 0.f, pd = 0.f;
#pragma unroll
  for (int i = 0; i < VEC; ++i) {
    float hv = row[i];
    ps += hv * asrc[i];
    pd += hv * adst[i];
  }
#pragma unroll
  for (int off = 1; off < 16; off <<= 1) {
    ps += __shfl_xor(ps, off, 64);
    pd += __shfl_xor(pd, off, 64);
  }
  if ((lane & 15) == 0) {
    al_s[node * 4 + head] = ps;
    al_d[node * 4 + head] = pd;
  }
}

// ---------------- layer-1 aggregation (concat + bias + leaky_relu) ----------
// One wave per node; lane l owns channels l*4..l*4+3, all in head l>>4.
__global__ __launch_bounds__(256) void gat_agg1(const float* __restrict__ h,
                                                const float* __restrict__ als,
                                                const float* __restrict__ aldv,
                                                const int* __restrict__ offs,
                                                const int* __restrict__ csr,
                                                const float* __restrict__ b1,
                                                float* __restrict__ out, int Nn) {
  int node = blockIdx.x * 4 + (threadIdx.x >> 6);
  if (node >= Nn) return;
  int lane = threadIdx.x & 63;
  int head = lane >> 4;
  float ald = aldv[node * 4 + head];
  float e0 = lrelu(als[node * 4 + head] + ald);
  float m = e0, s = 1.f;  // self-loop init: p_self = exp(0) = 1
  float4 acc = *(const float4*)(h + (size_t)node * 256 + lane * 4);
  int beg = offs[node], end = offs[node + 1];
  for (int k = beg; k < end; ++k) {
    int src = csr[k];
    float e = lrelu(als[src * 4 + head] + ald);
    float4 hv = *(const float4*)(h + (size_t)src * 256 + lane * 4);
    float mn = fmaxf(m, e);
    float sc = __expf(m - mn);
    float p = __expf(e - mn);
    s = s * sc + p;
    acc.x = acc.x * sc + p * hv.x;
    acc.y = acc.y * sc + p * hv.y;
    acc.z = acc.z * sc + p * hv.z;
    acc.w = acc.w * sc + p * hv.w;
    m = mn;
  }
  float inv = 1.f / s;
  const float4 bb = *(const float4*)(b1 + lane * 4);
  float4 o;
  o.x = lrelu(acc.x * inv + bb.x);
  o.y = lrelu(acc.y * inv + bb.y);
  o.z = lrelu(acc.z * inv + bb.z);
  o.w = lrelu(acc.w * inv + bb.w);
  *(float4*)(out + (size_t)node * 256 + lane * 4) = o;
}

// ---------------- layer-2 aggregation (mean over heads + bias) --------------
__global__ __launch_bounds__(256) void gat_agg2(const float* __restrict__ h,
                                                const float* __restrict__ als,
                                                const float* __restrict__ aldv,
                                                const int* __restrict__ offs,
                                                const int* __restrict__ csr,
                                                const float* __restrict__ b2,
                                                float* __restrict__ out, int Nn) {
  int node = blockIdx.x * 4 + (threadIdx.x >> 6);
  if (node >= Nn) return;
  int lane = threadIdx.x & 63;
  int head = lane >> 4;
  float ald = aldv[node * 4 + head];
  float e0 = lrelu(als[node * 4 + head] + ald);
  float m = e0, s = 1.f;
  float2 acc = *(const float2*)(h + (size_t)node * 128 + lane * 2);
  int beg = offs[node], end = offs[node + 1];
  for (int k = beg; k < end; ++k) {
    int src = csr[k];
    float e = lrelu(als[src * 4 + head] + ald);
    float2 hv = *(const float2*)(h + (size_t)src * 128 + lane * 2);
    float mn = fmaxf(m, e);
    float sc = __expf(m - mn);
    float p = __expf(e - mn);
    s = s * sc + p;
    acc.x = acc.x * sc + p * hv.x;
    acc.y = acc.y * sc + p * hv.y;
    m = mn;
  }
  float inv = 1.f / s;
  float vx = acc.x * inv, vy = acc.y * inv;
  vx += __shfl_xor(vx, 16, 64);
  vx += __shfl_xor(vx, 32, 64);
  vy += __shfl_xor(vy, 16, 64);
  vy += __shfl_xor(vy, 32, 64);
  if (lane < 16) {
    float2 o;
    o.x = vx * 0.25f + b2[lane * 2 + 0];
    o.y = vy * 0.25f + b2[lane * 2 + 1];
    *(float2*)(out + (size_t)node * 32 + lane * 2) = o;
  }
}

extern "C" void kernel_launch(void* const* d_in, const int* in_sizes, int n_in,
                              void* d_out, int out_size, void* d_ws, size_t ws_size,
                              hipStream_t stream) {
  const float* x   = (const float*)d_in[0];
  const int*   ei  = (const int*)d_in[1];
  const float* W1  = (const float*)d_in[2];
  const float* as1 = (const float*)d_in[3];
  const float* ad1 = (const float*)d_in[4];
  const float* b1  = (const float*)d_in[5];
  const float* W2  = (const float*)d_in[6];
  const float* as2 = (const float*)d_in[7];
  const float* ad2 = (const float*)d_in[8];
  const float* b2  = (const float*)d_in[9];
  float* out = (float*)d_out;

  const int CIN = 256, HD1 = 256, HD2 = 128;
  const int Nn = in_sizes[0] / CIN;  // 50000
  const int E  = in_sizes[1] / 2;    // 800000

  char* p = (char*)d_ws;
  float* h1   = (float*)p; p += (size_t)Nn * HD1 * 4;
  float* hact = (float*)p; p += (size_t)Nn * HD1 * 4;
  float* als1 = (float*)p; p += (size_t)Nn * 4 * 4;
  float* ald1 = (float*)p; p += (size_t)Nn * 4 * 4;
  float* als2 = (float*)p; p += (size_t)Nn * 4 * 4;
  float* ald2 = (float*)p; p += (size_t)Nn * 4 * 4;
  int* cnt  = (int*)p; p += (size_t)Nn * 4;
  int* offs = (int*)p; p += (size_t)(Nn + 1) * 4;
  int* cur  = (int*)p; p += (size_t)Nn * 4;
  int* csr  = (int*)p; p += (size_t)E * 4;
  float* h2 = h1;  // h1 dead after layer-1 aggregation; reuse for layer-2 features

  const int* esrc = ei;
  const int* edst = ei + E;

  // ---- CSR build (shared by both layers) ----
  hipMemsetAsync(cnt, 0, (size_t)Nn * sizeof(int), stream);
  hist_kernel<<<2048, 256, 0, stream>>>(edst, cnt, E);
  scan_kernel<<<1, 256, 0, stream>>>(cnt, offs, cur, Nn);
  scatter_kernel<<<2048, 256, 0, stream>>>(esrc, edst, cur, csr, E);

  // ---- layer 1 ----
  gemm_f32<<<dim3(HD1 / 64, (Nn + 63) / 64), 256, 0, stream>>>(x, W1, h1, Nn, HD1, CIN);
  compute_al<64, 4><<<(Nn + 3) / 4, 256, 0, stream>>>(h1, as1, ad1, als1, ald1, Nn);
  gat_agg1<<<(Nn + 3) / 4, 256, 0, stream>>>(h1, als1, ald1, offs, csr, b1, hact, Nn);

  // ---- layer 2 ----
  gemm_f32<<<dim3(HD2 / 64, (Nn + 63) / 64), 256, 0, stream>>>(hact, W2, h2, Nn, HD2, CIN);
  compute_al<32, 2><<<(Nn + 3) / 4, 256, 0, stream>>>(h2, as2, ad2, als2, ald2, Nn);
  gat_agg2<<<(Nn + 3) / 4, 256, 0, stream>>>(h2, als2, ald2, offs, csr, b2, out, Nn);
}

// Round 6
// 526.067 us; speedup vs baseline: 1.1890x; 1.1890x over previous
//
#include <hip/hip_runtime.h>
#include <hip/hip_fp16.h>

#define NEG_SLOPE_F 0.2f

typedef __attribute__((ext_vector_type(8))) short bf16x8;
typedef __attribute__((ext_vector_type(4))) float f32x4;

__device__ __forceinline__ float lrelu(float v) { return v > 0.0f ? v : NEG_SLOPE_F * v; }

__device__ __forceinline__ unsigned short f2bf(float f) {
  unsigned int u = __float_as_uint(f);
  u += 0x7FFFu + ((u >> 16) & 1u);  // round-to-nearest-even
  return (unsigned short)(u >> 16);
}
__device__ __forceinline__ float bf2f(unsigned short s) {
  return __uint_as_float(((unsigned int)s) << 16);
}

// ---------------- CSR construction ----------------
__global__ void hist_kernel(const int* __restrict__ dst, int* __restrict__ cnt, int E) {
  for (int i = blockIdx.x * blockDim.x + threadIdx.x; i < E; i += gridDim.x * blockDim.x)
    atomicAdd(&cnt[dst[i]], 1);
}

__global__ void scan_kernel(const int* __restrict__ cnt, int* __restrict__ offs,
                            int* __restrict__ cur, int Nn) {
  __shared__ int part[256];
  __shared__ int base[256];
  int tid = threadIdx.x;
  int per = (Nn + 255) / 256;
  int b = tid * per;
  int e = min(b + per, Nn);
  int s = 0;
  for (int i = b; i < e; ++i) s += cnt[i];
  part[tid] = s;
  __syncthreads();
  if (tid == 0) {
    int run = 0;
    for (int i = 0; i < 256; ++i) { base[i] = run; run += part[i]; }
    offs[Nn] = run;
  }
  __syncthreads();
  int run = base[tid];
  for (int i = b; i < e; ++i) { offs[i] = run; cur[i] = run; run += cnt[i]; }
}

__global__ void scatter_kernel(const int* __restrict__ src, const int* __restrict__ dst,
                               int* __restrict__ cur, int* __restrict__ csr, int E) {
  for (int i = blockIdx.x * blockDim.x + threadIdx.x; i < E; i += gridDim.x * blockDim.x) {
    int p = atomicAdd(&cur[dst[i]], 1);
    csr[p] = src[i];
  }
}

// ---------------- operand prep for bf16-split GEMM ----------------
// A' row layout: [hi(256) | lo(256)] bf16 per source row of 256 fp32.
__global__ void split_x_kernel(const float* __restrict__ src, unsigned short* __restrict__ dst,
                               int rows) {
  int total = rows * 64;  // groups of 4 elems
  for (int i = blockIdx.x * blockDim.x + threadIdx.x; i < total; i += gridDim.x * blockDim.x) {
    int r = i >> 6, c = (i & 63) * 4;
    float4 v = *(const float4*)(src + (size_t)r * 256 + c);
    unsigned short h0 = f2bf(v.x), h1 = f2bf(v.y), h2 = f2bf(v.z), h3 = f2bf(v.w);
    short4 hv = make_short4((short)h0, (short)h1, (short)h2, (short)h3);
    short4 lv = make_short4((short)f2bf(v.x - bf2f(h0)), (short)f2bf(v.y - bf2f(h1)),
                            (short)f2bf(v.z - bf2f(h2)), (short)f2bf(v.w - bf2f(h3)));
    *(short4*)(dst + (size_t)r * 512 + c) = hv;
    *(short4*)(dst + (size_t)r * 512 + 256 + c) = lv;
  }
}

// W[K=256][N] -> Bt[N][768]: k'<256 hi, 256..511 hi (dup), 512..767 lo.
__global__ void build_bt_kernel(const float* __restrict__ W, unsigned short* __restrict__ Bt,
                                int N) {
  int total = N * 256;
  for (int i = blockIdx.x * blockDim.x + threadIdx.x; i < total; i += gridDim.x * blockDim.x) {
    int n = i >> 8, k = i & 255;
    float v = W[(size_t)k * N + n];
    unsigned short hi = f2bf(v);
    unsigned short lo = f2bf(v - bf2f(hi));
    Bt[(size_t)n * 768 + k] = hi;
    Bt[(size_t)n * 768 + 256 + k] = hi;
    Bt[(size_t)n * 768 + 512 + k] = lo;
  }
}

// ---------------- bf16-split MFMA GEMM ----------------
// C[M,N] (+fp16 copy) = A'[Mpad,512](hi|lo) x Bt[N,768] over K'=768 with
// A col map: k'<512 -> k', else k'-512. 128x128 tile, 4 waves (2x2), BK=32.
__global__ __launch_bounds__(256) void gemm_split(const unsigned short* __restrict__ A,
                                                  const unsigned short* __restrict__ Bt,
                                                  float* __restrict__ C,
                                                  __half* __restrict__ Ch,
                                                  int M, int N) {
  __shared__ unsigned short As[128 * 32];
  __shared__ unsigned short Bs[128 * 32];
  const int tid = threadIdx.x;
  const int lane = tid & 63;
  const int wave = tid >> 6;
  const int wm = (wave >> 1) * 64;
  const int wn = (wave & 1) * 64;
  const int bm = blockIdx.y * 128;
  const int bn = blockIdx.x * 128;
  const int fr = lane & 15;
  const int q = lane >> 4;
  const int srow = tid >> 2;   // 0..63
  const int sslot = tid & 3;
  f32x4 acc[4][4] = {};
  for (int kt = 0; kt < 24; ++kt) {
    const int kA = (kt < 16 ? kt : kt - 16) * 32;
    const int kB = kt * 32;
#pragma unroll
    for (int i = 0; i < 2; ++i) {
      int r = i * 64 + srow;
      int sl = sslot ^ (r & 3);
      __builtin_amdgcn_global_load_lds(
          (const __attribute__((address_space(1))) unsigned int*)(A + (size_t)(bm + r) * 512 + kA + sl * 8),
          (__attribute__((address_space(3))) unsigned int*)((char*)As + i * 4096 + wave * 1024),
          16, 0, 0);
    }
#pragma unroll
    for (int i = 0; i < 2; ++i) {
      int r = i * 64 + srow;
      int sl = sslot ^ (r & 3);
      __builtin_amdgcn_global_load_lds(
          (const __attribute__((address_space(1))) unsigned int*)(Bt + (size_t)(bn + r) * 768 + kB + sl * 8),
          (__attribute__((address_space(3))) unsigned int*)((char*)Bs + i * 4096 + wave * 1024),
          16, 0, 0);
    }
    __syncthreads();  // drains vmcnt -> LDS tiles ready
    bf16x8 af[4], bfv[4];
#pragma unroll
    for (int mi = 0; mi < 4; ++mi) {
      int r = wm + mi * 16 + fr;
      af[mi] = *(const bf16x8*)(As + r * 32 + (q ^ (r & 3)) * 8);
    }
#pragma unroll
    for (int ni = 0; ni < 4; ++ni) {
      int r = wn + ni * 16 + fr;
      bfv[ni] = *(const bf16x8*)(Bs + r * 32 + (q ^ (r & 3)) * 8);
    }
#pragma unroll
    for (int mi = 0; mi < 4; ++mi)
#pragma unroll
      for (int ni = 0; ni < 4; ++ni)
        acc[mi][ni] = __builtin_amdgcn_mfma_f32_16x16x32_bf16(af[mi], bfv[ni], acc[mi][ni], 0, 0, 0);
    __syncthreads();  // compute done before next-stage overwrite
  }
#pragma unroll
  for (int mi = 0; mi < 4; ++mi) {
#pragma unroll
    for (int ni = 0; ni < 4; ++ni) {
      int col = bn + wn + ni * 16 + fr;
#pragma unroll
      for (int r = 0; r < 4; ++r) {
        int row = bm + wm + mi * 16 + q * 4 + r;
        if (row < M) {
          float v = acc[mi][ni][r];
          C[(size_t)row * N + col] = v;
          Ch[(size_t)row * N + col] = __float2half(v);
        }
      }
    }
  }
}

// ---------------- per-node attention logits (fp32 features) ----------------
template <int D, int VEC>
__global__ void compute_al(const float* __restrict__ h, const float* __restrict__ a_src,
                           const float* __restrict__ a_dst, float* __restrict__ al_s,
                           float* __restrict__ al_d, int Nn) {
  int node = blockIdx.x * (blockDim.x >> 6) + (threadIdx.x >> 6);
  if (node >= Nn) return;
  int lane = threadIdx.x & 63;
  int head = lane >> 4;
  const float* row = h + (size_t)node * (4 * D) + lane * VEC;
  const float* asrc = a_src + head * D + (lane & 15) * VEC;
  const float* adst = a_dst + head * D + (lane & 15) * VEC;
  float ps = 0.f, pd = 0.f;
#pragma unroll
  for (int i = 0; i < VEC; ++i) {
    float hv = row[i];
    ps += hv * asrc[i];
    pd += hv * adst[i];
  }
#pragma unroll
  for (int off = 1; off < 16; off <<= 1) {
    ps += __shfl_xor(ps, off, 64);
    pd += __shfl_xor(pd, off, 64);
  }
  if ((lane & 15) == 0) {
    al_s[node * 4 + head] = ps;
    al_d[node * 4 + head] = pd;
  }
}

// ---------------- layer-1 aggregation (fp16 gather -> bf16 hi/lo output) ----
__global__ __launch_bounds__(256) void gat_agg1(const __half* __restrict__ hg,
                                                const float* __restrict__ als,
                                                const float* __restrict__ aldv,
                                                const int* __restrict__ offs,
                                                const int* __restrict__ csr,
                                                const float* __restrict__ b1,
                                                unsigned short* __restrict__ A2, int Nn) {
  int node = blockIdx.x * 4 + (threadIdx.x >> 6);
  if (node >= Nn) return;
  int lane = threadIdx.x & 63;
  int head = lane >> 4;
  float ald = aldv[node * 4 + head];
  float m = lrelu(als[node * 4 + head] + ald);
  float s = 1.f;  // self-loop: exp(0)
  float2 rv = *(const float2*)(hg + (size_t)node * 256 + lane * 4);
  float2 fa = __half22float2(*(__half2*)&rv.x);
  float2 fb = __half22float2(*(__half2*)&rv.y);
  float4 acc = make_float4(fa.x, fa.y, fb.x, fb.y);
  int beg = offs[node], end = offs[node + 1];
  for (int k = beg; k < end; ++k) {
    int src = csr[k];
    float e = lrelu(als[src * 4 + head] + ald);
    float2 gv = *(const float2*)(hg + (size_t)src * 256 + lane * 4);
    float2 ga = __half22float2(*(__half2*)&gv.x);
    float2 gb = __half22float2(*(__half2*)&gv.y);
    float mn = fmaxf(m, e);
    float sc = __expf(m - mn);
    float p = __expf(e - mn);
    s = s * sc + p;
    acc.x = acc.x * sc + p * ga.x;
    acc.y = acc.y * sc + p * ga.y;
    acc.z = acc.z * sc + p * gb.x;
    acc.w = acc.w * sc + p * gb.y;
    m = mn;
  }
  float inv = 1.f / s;
  const float4 bb = *(const float4*)(b1 + lane * 4);
  float o0 = lrelu(acc.x * inv + bb.x);
  float o1 = lrelu(acc.y * inv + bb.y);
  float o2 = lrelu(acc.z * inv + bb.z);
  float o3 = lrelu(acc.w * inv + bb.w);
  unsigned short h0 = f2bf(o0), h1 = f2bf(o1), h2 = f2bf(o2), h3 = f2bf(o3);
  short4 hv = make_short4((short)h0, (short)h1, (short)h2, (short)h3);
  short4 lv = make_short4((short)f2bf(o0 - bf2f(h0)), (short)f2bf(o1 - bf2f(h1)),
                          (short)f2bf(o2 - bf2f(h2)), (short)f2bf(o3 - bf2f(h3)));
  *(short4*)(A2 + (size_t)node * 512 + lane * 4) = hv;
  *(short4*)(A2 + (size_t)node * 512 + 256 + lane * 4) = lv;
}

// ---------------- layer-2 aggregation (fp16 gather, mean heads + bias) ------
__global__ __launch_bounds__(256) void gat_agg2(const __half* __restrict__ hg,
                                                const float* __restrict__ als,
                                                const float* __restrict__ aldv,
                                                const int* __restrict__ offs,
                                                const int* __restrict__ csr,
                                                const float* __restrict__ b2,
                                                float* __restrict__ out, int Nn) {
  int node = blockIdx.x * 4 + (threadIdx.x >> 6);
  if (node >= Nn) return;
  int lane = threadIdx.x & 63;
  int head = lane >> 4;
  float ald = aldv[node * 4 + head];
  float m = lrelu(als[node * 4 + head] + ald);
  float s = 1.f;
  float2 acc = __half22float2(*(const __half2*)(hg + (size_t)node * 128 + lane * 2));
  int beg = offs[node], end = offs[node + 1];
  for (int k = beg; k < end; ++k) {
    int src = csr[k];
    float e = lrelu(als[src * 4 + head] + ald);
    float2 hv = __half22float2(*(const __half2*)(hg + (size_t)src * 128 + lane * 2));
    float mn = fmaxf(m, e);
    float sc = __expf(m - mn);
    float p = __expf(e - mn);
    s = s * sc + p;
    acc.x = acc.x * sc + p * hv.x;
    acc.y = acc.y * sc + p * hv.y;
    m = mn;
  }
  float inv = 1.f / s;
  float vx = acc.x * inv, vy = acc.y * inv;
  vx += __shfl_xor(vx, 16, 64);
  vx += __shfl_xor(vx, 32, 64);
  vy += __shfl_xor(vy, 16, 64);
  vy += __shfl_xor(vy, 32, 64);
  if (lane < 16) {
    float2 o;
    o.x = vx * 0.25f + b2[lane * 2 + 0];
    o.y = vy * 0.25f + b2[lane * 2 + 1];
    *(float2*)(out + (size_t)node * 32 + lane * 2) = o;
  }
}

extern "C" void kernel_launch(void* const* d_in, const int* in_sizes, int n_in,
                              void* d_out, int out_size, void* d_ws, size_t ws_size,
                              hipStream_t stream) {
  const float* x   = (const float*)d_in[0];
  const int*   ei  = (const int*)d_in[1];
  const float* W1  = (const float*)d_in[2];
  const float* as1 = (const float*)d_in[3];
  const float* ad1 = (const float*)d_in[4];
  const float* b1  = (const float*)d_in[5];
  const float* W2  = (const float*)d_in[6];
  const float* as2 = (const float*)d_in[7];
  const float* ad2 = (const float*)d_in[8];
  const float* b2  = (const float*)d_in[9];
  float* out = (float*)d_out;

  const int CIN = 256, HD1 = 256, HD2 = 128;
  const int Nn = in_sizes[0] / CIN;   // 50000
  const int E  = in_sizes[1] / 2;     // 800000
  const int Mpad = (Nn + 127) & ~127; // 50048

  char* p = (char*)d_ws;
  unsigned short* A12 = (unsigned short*)p; p += (size_t)Mpad * 512 * 2;  // x-split, then hact-split
  float*  hf = (float*)p;  p += (size_t)Nn * 256 * 4;  // h1 fp32, reused as h2 fp32
  __half* hg = (__half*)p; p += (size_t)Nn * 256 * 2;  // h1 fp16, reused as h2 fp16
  unsigned short* Bt1 = (unsigned short*)p; p += (size_t)256 * 768 * 2;
  unsigned short* Bt2 = (unsigned short*)p; p += (size_t)128 * 768 * 2;
  float* als1 = (float*)p; p += (size_t)Nn * 4 * 4;
  float* ald1 = (float*)p; p += (size_t)Nn * 4 * 4;
  float* als2 = (float*)p; p += (size_t)Nn * 4 * 4;
  float* ald2 = (float*)p; p += (size_t)Nn * 4 * 4;
  int* cnt  = (int*)p; p += (size_t)Nn * 4;
  int* offs = (int*)p; p += (size_t)(Nn + 1) * 4;
  int* cur  = (int*)p; p += (size_t)Nn * 4;
  int* csr  = (int*)p; p += (size_t)E * 4;

  const int* esrc = ei;
  const int* edst = ei + E;

  // ---- CSR build ----
  hipMemsetAsync(cnt, 0, (size_t)Nn * sizeof(int), stream);
  hist_kernel<<<2048, 256, 0, stream>>>(edst, cnt, E);
  scan_kernel<<<1, 256, 0, stream>>>(cnt, offs, cur, Nn);
  scatter_kernel<<<2048, 256, 0, stream>>>(esrc, edst, cur, csr, E);

  // ---- operand prep ----
  hipMemsetAsync(A12 + (size_t)Nn * 512, 0, (size_t)(Mpad - Nn) * 512 * 2, stream);
  split_x_kernel<<<2048, 256, 0, stream>>>(x, A12, Nn);
  build_bt_kernel<<<256, 256, 0, stream>>>(W1, Bt1, HD1);
  build_bt_kernel<<<128, 256, 0, stream>>>(W2, Bt2, HD2);

  // ---- layer 1 ----
  gemm_split<<<dim3(HD1 / 128, Mpad / 128), 256, 0, stream>>>(A12, Bt1, hf, hg, Nn, HD1);
  compute_al<64, 4><<<(Nn + 3) / 4, 256, 0, stream>>>(hf, as1, ad1, als1, ald1, Nn);
  gat_agg1<<<(Nn + 3) / 4, 256, 0, stream>>>(hg, als1, ald1, offs, csr, b1, A12, Nn);

  // ---- layer 2 ----
  gemm_split<<<dim3(HD2 / 128, Mpad / 128), 256, 0, stream>>>(A12, Bt2, hf, hg, Nn, HD2);
  compute_al<32, 2><<<(Nn + 3) / 4, 256, 0, stream>>>(hf, as2, ad2, als2, ald2, Nn);
  gat_agg2<<<(Nn + 3) / 4, 256, 0, stream>>>(hg, als2, ald2, offs, csr, b2, out, Nn);
}

// Round 7
// 410.517 us; speedup vs baseline: 1.5237x; 1.2815x over previous
//
#include <hip/hip_runtime.h>
#include <hip/hip_fp16.h>

#define NEG_SLOPE_F 0.2f

typedef __attribute__((ext_vector_type(8))) short bf16x8;
typedef __attribute__((ext_vector_type(4))) float f32x4;

__device__ __forceinline__ float lrelu(float v) { return v > 0.0f ? v : NEG_SLOPE_F * v; }

__device__ __forceinline__ unsigned short f2bf(float f) {
  unsigned int u = __float_as_uint(f);
  u += 0x7FFFu + ((u >> 16) & 1u);  // round-to-nearest-even
  return (unsigned short)(u >> 16);
}
__device__ __forceinline__ float bf2f(unsigned short s) {
  return __uint_as_float(((unsigned int)s) << 16);
}

// ---------------- CSR construction ----------------
__global__ void hist_kernel(const int* __restrict__ dst, int* __restrict__ cnt, int E) {
  for (int i = blockIdx.x * blockDim.x + threadIdx.x; i < E; i += gridDim.x * blockDim.x)
    atomicAdd(&cnt[dst[i]], 1);
}

// --- hierarchical exclusive scan over cnt[0..Nn) -> offs, cur; offs[Nn]=E ---
// k1: per-256-chunk sums
__global__ void chunk_sum_kernel(const int* __restrict__ cnt, int* __restrict__ bsum, int Nn) {
  __shared__ int sm[256];
  int t = threadIdx.x;
  int i = blockIdx.x * 256 + t;
  sm[t] = (i < Nn) ? cnt[i] : 0;
  __syncthreads();
  for (int off = 128; off > 0; off >>= 1) {
    if (t < off) sm[t] += sm[t + off];
    __syncthreads();
  }
  if (t == 0) bsum[blockIdx.x] = sm[0];
}

// k2: single-block exclusive scan of the (<=256) chunk sums
__global__ void scan_base_kernel(const int* __restrict__ bsum, int* __restrict__ bbase,
                                 int* __restrict__ offs, int nchunk, int Nn) {
  __shared__ int sm[256];
  int t = threadIdx.x;
  int v = (t < nchunk) ? bsum[t] : 0;
  sm[t] = v;
  __syncthreads();
  for (int off = 1; off < 256; off <<= 1) {
    int x = (t >= off) ? sm[t - off] : 0;
    __syncthreads();
    sm[t] += x;
    __syncthreads();
  }
  if (t < nchunk) bbase[t] = sm[t] - v;  // exclusive base for chunk t
  if (t == 255) offs[Nn] = sm[255];      // grand total
}

// k3: per-chunk intra-block exclusive scan + chunk base
__global__ void chunk_scan_kernel(const int* __restrict__ cnt, const int* __restrict__ bbase,
                                  int* __restrict__ offs, int* __restrict__ cur, int Nn) {
  __shared__ int sm[256];
  int t = threadIdx.x;
  int i = blockIdx.x * 256 + t;
  int v = (i < Nn) ? cnt[i] : 0;
  sm[t] = v;
  __syncthreads();
  for (int off = 1; off < 256; off <<= 1) {
    int x = (t >= off) ? sm[t - off] : 0;
    __syncthreads();
    sm[t] += x;
    __syncthreads();
  }
  if (i < Nn) {
    int ex = bbase[blockIdx.x] + sm[t] - v;
    offs[i] = ex;
    cur[i] = ex;
  }
}

__global__ void scatter_kernel(const int* __restrict__ src, const int* __restrict__ dst,
                               int* __restrict__ cur, int* __restrict__ csr, int E) {
  for (int i = blockIdx.x * blockDim.x + threadIdx.x; i < E; i += gridDim.x * blockDim.x) {
    int p = atomicAdd(&cur[dst[i]], 1);
    csr[p] = src[i];
  }
}

// ---------------- operand prep for bf16-split GEMM ----------------
// A' row layout: [hi(256) | lo(256)] bf16 per source row of 256 fp32.
__global__ void split_x_kernel(const float* __restrict__ src, unsigned short* __restrict__ dst,
                               int rows) {
  int total = rows * 64;  // groups of 4 elems
  for (int i = blockIdx.x * blockDim.x + threadIdx.x; i < total; i += gridDim.x * blockDim.x) {
    int r = i >> 6, c = (i & 63) * 4;
    float4 v = *(const float4*)(src + (size_t)r * 256 + c);
    unsigned short h0 = f2bf(v.x), h1 = f2bf(v.y), h2 = f2bf(v.z), h3 = f2bf(v.w);
    short4 hv = make_short4((short)h0, (short)h1, (short)h2, (short)h3);
    short4 lv = make_short4((short)f2bf(v.x - bf2f(h0)), (short)f2bf(v.y - bf2f(h1)),
                            (short)f2bf(v.z - bf2f(h2)), (short)f2bf(v.w - bf2f(h3)));
    *(short4*)(dst + (size_t)r * 512 + c) = hv;
    *(short4*)(dst + (size_t)r * 512 + 256 + c) = lv;
  }
}

// W[K=256][N] -> Bt[N][768]: k'<256 hi, 256..511 hi (dup), 512..767 lo.
__global__ void build_bt_kernel(const float* __restrict__ W, unsigned short* __restrict__ Bt,
                                int N) {
  int total = N * 256;
  for (int i = blockIdx.x * blockDim.x + threadIdx.x; i < total; i += gridDim.x * blockDim.x) {
    int n = i >> 8, k = i & 255;
    float v = W[(size_t)k * N + n];
    unsigned short hi = f2bf(v);
    unsigned short lo = f2bf(v - bf2f(hi));
    Bt[(size_t)n * 768 + k] = hi;
    Bt[(size_t)n * 768 + 256 + k] = hi;
    Bt[(size_t)n * 768 + 512 + k] = lo;
  }
}

// ---------------- bf16-split MFMA GEMM ----------------
// C[M,N] (+fp16 copy) = A'[Mpad,512](hi|lo) x Bt[N,768] over K'=768 with
// A col map: k'<512 -> k', else k'-512. 128x128 tile, 4 waves (2x2), BK=32.
__global__ __launch_bounds__(256) void gemm_split(const unsigned short* __restrict__ A,
                                                  const unsigned short* __restrict__ Bt,
                                                  float* __restrict__ C,
                                                  __half* __restrict__ Ch,
                                                  int M, int N) {
  __shared__ unsigned short As[128 * 32];
  __shared__ unsigned short Bs[128 * 32];
  const int tid = threadIdx.x;
  const int lane = tid & 63;
  const int wave = tid >> 6;
  const int wm = (wave >> 1) * 64;
  const int wn = (wave & 1) * 64;
  const int bm = blockIdx.y * 128;
  const int bn = blockIdx.x * 128;
  const int fr = lane & 15;
  const int q = lane >> 4;
  const int srow = tid >> 2;   // 0..63
  const int sslot = tid & 3;
  f32x4 acc[4][4] = {};
  for (int kt = 0; kt < 24; ++kt) {
    const int kA = (kt < 16 ? kt : kt - 16) * 32;
    const int kB = kt * 32;
#pragma unroll
    for (int i = 0; i < 2; ++i) {
      int r = i * 64 + srow;
      int sl = sslot ^ (r & 3);
      __builtin_amdgcn_global_load_lds(
          (const __attribute__((address_space(1))) unsigned int*)(A + (size_t)(bm + r) * 512 + kA + sl * 8),
          (__attribute__((address_space(3))) unsigned int*)((char*)As + i * 4096 + wave * 1024),
          16, 0, 0);
    }
#pragma unroll
    for (int i = 0; i < 2; ++i) {
      int r = i * 64 + srow;
      int sl = sslot ^ (r & 3);
      __builtin_amdgcn_global_load_lds(
          (const __attribute__((address_space(1))) unsigned int*)(Bt + (size_t)(bn + r) * 768 + kB + sl * 8),
          (__attribute__((address_space(3))) unsigned int*)((char*)Bs + i * 4096 + wave * 1024),
          16, 0, 0);
    }
    __syncthreads();  // drains vmcnt -> LDS tiles ready
    bf16x8 af[4], bfv[4];
#pragma unroll
    for (int mi = 0; mi < 4; ++mi) {
      int r = wm + mi * 16 + fr;
      af[mi] = *(const bf16x8*)(As + r * 32 + (q ^ (r & 3)) * 8);
    }
#pragma unroll
    for (int ni = 0; ni < 4; ++ni) {
      int r = wn + ni * 16 + fr;
      bfv[ni] = *(const bf16x8*)(Bs + r * 32 + (q ^ (r & 3)) * 8);
    }
#pragma unroll
    for (int mi = 0; mi < 4; ++mi)
#pragma unroll
      for (int ni = 0; ni < 4; ++ni)
        acc[mi][ni] = __builtin_amdgcn_mfma_f32_16x16x32_bf16(af[mi], bfv[ni], acc[mi][ni], 0, 0, 0);
    __syncthreads();  // compute done before next-stage overwrite
  }
#pragma unroll
  for (int mi = 0; mi < 4; ++mi) {
#pragma unroll
    for (int ni = 0; ni < 4; ++ni) {
      int col = bn + wn + ni * 16 + fr;
#pragma unroll
      for (int r = 0; r < 4; ++r) {
        int row = bm + wm + mi * 16 + q * 4 + r;
        if (row < M) {
          float v = acc[mi][ni][r];
          C[(size_t)row * N + col] = v;
          Ch[(size_t)row * N + col] = __float2half(v);
        }
      }
    }
  }
}

// ---------------- per-node attention logits (fp32 features) ----------------
template <int D, int VEC>
__global__ void compute_al(const float* __restrict__ h, const float* __restrict__ a_src,
                           const float* __restrict__ a_dst, float* __restrict__ al_s,
                           float* __restrict__ al_d, int Nn) {
  int node = blockIdx.x * (blockDim.x >> 6) + (threadIdx.x >> 6);
  if (node >= Nn) return;
  int lane = threadIdx.x & 63;
  int head = lane >> 4;
  const float* row = h + (size_t)node * (4 * D) + lane * VEC;
  const float* asrc = a_src + head * D + (lane & 15) * VEC;
  const float* adst = a_dst + head * D + (lane & 15) * VEC;
  float ps = 0.f, pd = 0.f;
#pragma unroll
  for (int i = 0; i < VEC; ++i) {
    float hv = row[i];
    ps += hv * asrc[i];
    pd += hv * adst[i];
  }
#pragma unroll
  for (int off = 1; off < 16; off <<= 1) {
    ps += __shfl_xor(ps, off, 64);
    pd += __shfl_xor(pd, off, 64);
  }
  if ((lane & 15) == 0) {
    al_s[node * 4 + head] = ps;
    al_d[node * 4 + head] = pd;
  }
}

// ---------------- layer-1 aggregation (fp16 gather -> bf16 hi/lo output) ----
__global__ __launch_bounds__(256) void gat_agg1(const __half* __restrict__ hg,
                                                const float* __restrict__ als,
                                                const float* __restrict__ aldv,
                                                const int* __restrict__ offs,
                                                const int* __restrict__ csr,
                                                const float* __restrict__ b1,
                                                unsigned short* __restrict__ A2, int Nn) {
  int node = blockIdx.x * 4 + (threadIdx.x >> 6);
  if (node >= Nn) return;
  int lane = threadIdx.x & 63;
  int head = lane >> 4;
  float ald = aldv[node * 4 + head];
  float m = lrelu(als[node * 4 + head] + ald);
  float s = 1.f;  // self-loop: exp(0)
  float2 rv = *(const float2*)(hg + (size_t)node * 256 + lane * 4);
  float2 fa = __half22float2(*(__half2*)&rv.x);
  float2 fb = __half22float2(*(__half2*)&rv.y);
  float4 acc = make_float4(fa.x, fa.y, fb.x, fb.y);
  int beg = offs[node], end = offs[node + 1];
  for (int k = beg; k < end; ++k) {
    int src = csr[k];
    float e = lrelu(als[src * 4 + head] + ald);
    float2 gv = *(const float2*)(hg + (size_t)src * 256 + lane * 4);
    float2 ga = __half22float2(*(__half2*)&gv.x);
    float2 gb = __half22float2(*(__half2*)&gv.y);
    float mn = fmaxf(m, e);
    float sc = __expf(m - mn);
    float p = __expf(e - mn);
    s = s * sc + p;
    acc.x = acc.x * sc + p * ga.x;
    acc.y = acc.y * sc + p * ga.y;
    acc.z = acc.z * sc + p * gb.x;
    acc.w = acc.w * sc + p * gb.y;
    m = mn;
  }
  float inv = 1.f / s;
  const float4 bb = *(const float4*)(b1 + lane * 4);
  float o0 = lrelu(acc.x * inv + bb.x);
  float o1 = lrelu(acc.y * inv + bb.y);
  float o2 = lrelu(acc.z * inv + bb.z);
  float o3 = lrelu(acc.w * inv + bb.w);
  unsigned short h0 = f2bf(o0), h1 = f2bf(o1), h2 = f2bf(o2), h3 = f2bf(o3);
  short4 hv = make_short4((short)h0, (short)h1, (short)h2, (short)h3);
  short4 lv = make_short4((short)f2bf(o0 - bf2f(h0)), (short)f2bf(o1 - bf2f(h1)),
                          (short)f2bf(o2 - bf2f(h2)), (short)f2bf(o3 - bf2f(h3)));
  *(short4*)(A2 + (size_t)node * 512 + lane * 4) = hv;
  *(short4*)(A2 + (size_t)node * 512 + 256 + lane * 4) = lv;
}

// ---------------- layer-2 aggregation (fp16 gather, mean heads + bias) ------
__global__ __launch_bounds__(256) void gat_agg2(const __half* __restrict__ hg,
                                                const float* __restrict__ als,
                                                const float* __restrict__ aldv,
                                                const int* __restrict__ offs,
                                                const int* __restrict__ csr,
                                                const float* __restrict__ b2,
                                                float* __restrict__ out, int Nn) {
  int node = blockIdx.x * 4 + (threadIdx.x >> 6);
  if (node >= Nn) return;
  int lane = threadIdx.x & 63;
  int head = lane >> 4;
  float ald = aldv[node * 4 + head];
  float m = lrelu(als[node * 4 + head] + ald);
  float s = 1.f;
  float2 acc = __half22float2(*(const __half2*)(hg + (size_t)node * 128 + lane * 2));
  int beg = offs[node], end = offs[node + 1];
  for (int k = beg; k < end; ++k) {
    int src = csr[k];
    float e = lrelu(als[src * 4 + head] + ald);
    float2 hv = __half22float2(*(const __half2*)(hg + (size_t)src * 128 + lane * 2));
    float mn = fmaxf(m, e);
    float sc = __expf(m - mn);
    float p = __expf(e - mn);
    s = s * sc + p;
    acc.x = acc.x * sc + p * hv.x;
    acc.y = acc.y * sc + p * hv.y;
    m = mn;
  }
  float inv = 1.f / s;
  float vx = acc.x * inv, vy = acc.y * inv;
  vx += __shfl_xor(vx, 16, 64);
  vx += __shfl_xor(vx, 32, 64);
  vy += __shfl_xor(vy, 16, 64);
  vy += __shfl_xor(vy, 32, 64);
  if (lane < 16) {
    float2 o;
    o.x = vx * 0.25f + b2[lane * 2 + 0];
    o.y = vy * 0.25f + b2[lane * 2 + 1];
    *(float2*)(out + (size_t)node * 32 + lane * 2) = o;
  }
}

extern "C" void kernel_launch(void* const* d_in, const int* in_sizes, int n_in,
                              void* d_out, int out_size, void* d_ws, size_t ws_size,
                              hipStream_t stream) {
  const float* x   = (const float*)d_in[0];
  const int*   ei  = (const int*)d_in[1];
  const float* W1  = (const float*)d_in[2];
  const float* as1 = (const float*)d_in[3];
  const float* ad1 = (const float*)d_in[4];
  const float* b1  = (const float*)d_in[5];
  const float* W2  = (const float*)d_in[6];
  const float* as2 = (const float*)d_in[7];
  const float* ad2 = (const float*)d_in[8];
  const float* b2  = (const float*)d_in[9];
  float* out = (float*)d_out;

  const int CIN = 256, HD1 = 256, HD2 = 128;
  const int Nn = in_sizes[0] / CIN;   // 50000
  const int E  = in_sizes[1] / 2;     // 800000
  const int Mpad = (Nn + 127) & ~127; // 50048
  const int nchunk = (Nn + 255) / 256;  // 196 (fits single-block base scan <=256)

  char* p = (char*)d_ws;
  unsigned short* A12 = (unsigned short*)p; p += (size_t)Mpad * 512 * 2;  // x-split, then hact-split
  float*  hf = (float*)p;  p += (size_t)Nn * 256 * 4;  // h1 fp32, reused as h2 fp32
  __half* hg = (__half*)p; p += (size_t)Nn * 256 * 2;  // h1 fp16, reused as h2 fp16
  unsigned short* Bt1 = (unsigned short*)p; p += (size_t)256 * 768 * 2;
  unsigned short* Bt2 = (unsigned short*)p; p += (size_t)128 * 768 * 2;
  float* als1 = (float*)p; p += (size_t)Nn * 4 * 4;
  float* ald1 = (float*)p; p += (size_t)Nn * 4 * 4;
  float* als2 = (float*)p; p += (size_t)Nn * 4 * 4;
  float* ald2 = (float*)p; p += (size_t)Nn * 4 * 4;
  int* cnt   = (int*)p; p += (size_t)Nn * 4;
  int* offs  = (int*)p; p += (size_t)(Nn + 1) * 4;
  int* cur   = (int*)p; p += (size_t)Nn * 4;
  int* bsum  = (int*)p; p += (size_t)256 * 4;
  int* bbase = (int*)p; p += (size_t)256 * 4;
  int* csr   = (int*)p; p += (size_t)E * 4;

  const int* esrc = ei;
  const int* edst = ei + E;

  // ---- CSR build (hierarchical scan) ----
  hipMemsetAsync(cnt, 0, (size_t)Nn * sizeof(int), stream);
  hist_kernel<<<2048, 256, 0, stream>>>(edst, cnt, E);
  chunk_sum_kernel<<<nchunk, 256, 0, stream>>>(cnt, bsum, Nn);
  scan_base_kernel<<<1, 256, 0, stream>>>(bsum, bbase, offs, nchunk, Nn);
  chunk_scan_kernel<<<nchunk, 256, 0, stream>>>(cnt, bbase, offs, cur, Nn);
  scatter_kernel<<<2048, 256, 0, stream>>>(esrc, edst, cur, csr, E);

  // ---- operand prep ----
  hipMemsetAsync(A12 + (size_t)Nn * 512, 0, (size_t)(Mpad - Nn) * 512 * 2, stream);
  split_x_kernel<<<2048, 256, 0, stream>>>(x, A12, Nn);
  build_bt_kernel<<<256, 256, 0, stream>>>(W1, Bt1, HD1);
  build_bt_kernel<<<128, 256, 0, stream>>>(W2, Bt2, HD2);

  // ---- layer 1 ----
  gemm_split<<<dim3(HD1 / 128, Mpad / 128), 256, 0, stream>>>(A12, Bt1, hf, hg, Nn, HD1);
  compute_al<64, 4><<<(Nn + 3) / 4, 256, 0, stream>>>(hf, as1, ad1, als1, ald1, Nn);
  gat_agg1<<<(Nn + 3) / 4, 256, 0, stream>>>(hg, als1, ald1, offs, csr, b1, A12, Nn);

  // ---- layer 2 ----
  gemm_split<<<dim3(HD2 / 128, Mpad / 128), 256, 0, stream>>>(A12, Bt2, hf, hg, Nn, HD2);
  compute_al<32, 2><<<(Nn + 3) / 4, 256, 0, stream>>>(hf, as2, ad2, als2, ald2, Nn);
  gat_agg2<<<(Nn + 3) / 4, 256, 0, stream>>>(hg, als2, ald2, offs, csr, b2, out, Nn);
}

// Round 8
// 331.518 us; speedup vs baseline: 1.8867x; 1.2383x over previous
//
#include <hip/hip_runtime.h>
#include <hip/hip_fp16.h>

#define NEG_SLOPE_F 0.2f

typedef __attribute__((ext_vector_type(8))) short bf16x8;
typedef __attribute__((ext_vector_type(4))) float f32x4;

__device__ __forceinline__ float lrelu(float v) { return v > 0.0f ? v : NEG_SLOPE_F * v; }

__device__ __forceinline__ unsigned short f2bf(float f) {
  unsigned int u = __float_as_uint(f);
  u += 0x7FFFu + ((u >> 16) & 1u);  // round-to-nearest-even
  return (unsigned short)(u >> 16);
}
__device__ __forceinline__ float bf2f(unsigned short s) {
  return __uint_as_float(((unsigned int)s) << 16);
}

// ---------------- CSR construction ----------------
__global__ void hist_kernel(const int* __restrict__ dst, int* __restrict__ cnt, int E) {
  for (int i = blockIdx.x * blockDim.x + threadIdx.x; i < E; i += gridDim.x * blockDim.x)
    atomicAdd(&cnt[dst[i]], 1);
}

// --- hierarchical exclusive scan over cnt[0..Nn) -> offs, cur; offs[Nn]=E ---
__global__ void chunk_sum_kernel(const int* __restrict__ cnt, int* __restrict__ bsum, int Nn) {
  __shared__ int sm[256];
  int t = threadIdx.x;
  int i = blockIdx.x * 256 + t;
  sm[t] = (i < Nn) ? cnt[i] : 0;
  __syncthreads();
  for (int off = 128; off > 0; off >>= 1) {
    if (t < off) sm[t] += sm[t + off];
    __syncthreads();
  }
  if (t == 0) bsum[blockIdx.x] = sm[0];
}

__global__ void scan_base_kernel(const int* __restrict__ bsum, int* __restrict__ bbase,
                                 int* __restrict__ offs, int nchunk, int Nn) {
  __shared__ int sm[256];
  int t = threadIdx.x;
  int v = (t < nchunk) ? bsum[t] : 0;
  sm[t] = v;
  __syncthreads();
  for (int off = 1; off < 256; off <<= 1) {
    int x = (t >= off) ? sm[t - off] : 0;
    __syncthreads();
    sm[t] += x;
    __syncthreads();
  }
  if (t < nchunk) bbase[t] = sm[t] - v;  // exclusive base for chunk t
  if (t == 255) offs[Nn] = sm[255];      // grand total
}

__global__ void chunk_scan_kernel(const int* __restrict__ cnt, const int* __restrict__ bbase,
                                  int* __restrict__ offs, int* __restrict__ cur, int Nn) {
  __shared__ int sm[256];
  int t = threadIdx.x;
  int i = blockIdx.x * 256 + t;
  int v = (i < Nn) ? cnt[i] : 0;
  sm[t] = v;
  __syncthreads();
  for (int off = 1; off < 256; off <<= 1) {
    int x = (t >= off) ? sm[t - off] : 0;
    __syncthreads();
    sm[t] += x;
    __syncthreads();
  }
  if (i < Nn) {
    int ex = bbase[blockIdx.x] + sm[t] - v;
    offs[i] = ex;
    cur[i] = ex;
  }
}

__global__ void scatter_kernel(const int* __restrict__ src, const int* __restrict__ dst,
                               int* __restrict__ cur, int* __restrict__ csr, int E) {
  for (int i = blockIdx.x * blockDim.x + threadIdx.x; i < E; i += gridDim.x * blockDim.x) {
    int p = atomicAdd(&cur[dst[i]], 1);
    csr[p] = src[i];
  }
}

// ---------------- operand prep for bf16-split GEMM ----------------
__global__ void split_x_kernel(const float* __restrict__ src, unsigned short* __restrict__ dst,
                               int rows) {
  int total = rows * 64;  // groups of 4 elems
  for (int i = blockIdx.x * blockDim.x + threadIdx.x; i < total; i += gridDim.x * blockDim.x) {
    int r = i >> 6, c = (i & 63) * 4;
    float4 v = *(const float4*)(src + (size_t)r * 256 + c);
    unsigned short h0 = f2bf(v.x), h1 = f2bf(v.y), h2 = f2bf(v.z), h3 = f2bf(v.w);
    short4 hv = make_short4((short)h0, (short)h1, (short)h2, (short)h3);
    short4 lv = make_short4((short)f2bf(v.x - bf2f(h0)), (short)f2bf(v.y - bf2f(h1)),
                            (short)f2bf(v.z - bf2f(h2)), (short)f2bf(v.w - bf2f(h3)));
    *(short4*)(dst + (size_t)r * 512 + c) = hv;
    *(short4*)(dst + (size_t)r * 512 + 256 + c) = lv;
  }
}

// W[K=256][N] -> Bt[N][768]: k'<256 hi, 256..511 hi (dup), 512..767 lo.
__global__ void build_bt_kernel(const float* __restrict__ W, unsigned short* __restrict__ Bt,
                                int N) {
  int total = N * 256;
  for (int i = blockIdx.x * blockDim.x + threadIdx.x; i < total; i += gridDim.x * blockDim.x) {
    int n = i >> 8, k = i & 255;
    float v = W[(size_t)k * N + n];
    unsigned short hi = f2bf(v);
    unsigned short lo = f2bf(v - bf2f(hi));
    Bt[(size_t)n * 768 + k] = hi;
    Bt[(size_t)n * 768 + 256 + k] = hi;
    Bt[(size_t)n * 768 + 512 + k] = lo;
  }
}

// ---------------- bf16-split MFMA GEMM ----------------
__global__ __launch_bounds__(256) void gemm_split(const unsigned short* __restrict__ A,
                                                  const unsigned short* __restrict__ Bt,
                                                  float* __restrict__ C,
                                                  __half* __restrict__ Ch,
                                                  int M, int N) {
  __shared__ unsigned short As[128 * 32];
  __shared__ unsigned short Bs[128 * 32];
  const int tid = threadIdx.x;
  const int lane = tid & 63;
  const int wave = tid >> 6;
  const int wm = (wave >> 1) * 64;
  const int wn = (wave & 1) * 64;
  const int bm = blockIdx.y * 128;
  const int bn = blockIdx.x * 128;
  const int fr = lane & 15;
  const int q = lane >> 4;
  const int srow = tid >> 2;   // 0..63
  const int sslot = tid & 3;
  f32x4 acc[4][4] = {};
  for (int kt = 0; kt < 24; ++kt) {
    const int kA = (kt < 16 ? kt : kt - 16) * 32;
    const int kB = kt * 32;
#pragma unroll
    for (int i = 0; i < 2; ++i) {
      int r = i * 64 + srow;
      int sl = sslot ^ (r & 3);
      __builtin_amdgcn_global_load_lds(
          (const __attribute__((address_space(1))) unsigned int*)(A + (size_t)(bm + r) * 512 + kA + sl * 8),
          (__attribute__((address_space(3))) unsigned int*)((char*)As + i * 4096 + wave * 1024),
          16, 0, 0);
    }
#pragma unroll
    for (int i = 0; i < 2; ++i) {
      int r = i * 64 + srow;
      int sl = sslot ^ (r & 3);
      __builtin_amdgcn_global_load_lds(
          (const __attribute__((address_space(1))) unsigned int*)(Bt + (size_t)(bn + r) * 768 + kB + sl * 8),
          (__attribute__((address_space(3))) unsigned int*)((char*)Bs + i * 4096 + wave * 1024),
          16, 0, 0);
    }
    __syncthreads();  // drains vmcnt -> LDS tiles ready
    bf16x8 af[4], bfv[4];
#pragma unroll
    for (int mi = 0; mi < 4; ++mi) {
      int r = wm + mi * 16 + fr;
      af[mi] = *(const bf16x8*)(As + r * 32 + (q ^ (r & 3)) * 8);
    }
#pragma unroll
    for (int ni = 0; ni < 4; ++ni) {
      int r = wn + ni * 16 + fr;
      bfv[ni] = *(const bf16x8*)(Bs + r * 32 + (q ^ (r & 3)) * 8);
    }
#pragma unroll
    for (int mi = 0; mi < 4; ++mi)
#pragma unroll
      for (int ni = 0; ni < 4; ++ni)
        acc[mi][ni] = __builtin_amdgcn_mfma_f32_16x16x32_bf16(af[mi], bfv[ni], acc[mi][ni], 0, 0, 0);
    __syncthreads();  // compute done before next-stage overwrite
  }
#pragma unroll
  for (int mi = 0; mi < 4; ++mi) {
#pragma unroll
    for (int ni = 0; ni < 4; ++ni) {
      int col = bn + wn + ni * 16 + fr;
#pragma unroll
      for (int r = 0; r < 4; ++r) {
        int row = bm + wm + mi * 16 + q * 4 + r;
        if (row < M) {
          float v = acc[mi][ni][r];
          C[(size_t)row * N + col] = v;
          Ch[(size_t)row * N + col] = __float2half(v);
        }
      }
    }
  }
}

// ---------------- per-node attention logits (fp32 features) ----------------
template <int D, int VEC>
__global__ void compute_al(const float* __restrict__ h, const float* __restrict__ a_src,
                           const float* __restrict__ a_dst, float* __restrict__ al_s,
                           float* __restrict__ al_d, int Nn) {
  int node = blockIdx.x * (blockDim.x >> 6) + (threadIdx.x >> 6);
  if (node >= Nn) return;
  int lane = threadIdx.x & 63;
  int head = lane >> 4;
  const float* row = h + (size_t)node * (4 * D) + lane * VEC;
  const float* asrc = a_src + head * D + (lane & 15) * VEC;
  const float* adst = a_dst + head * D + (lane & 15) * VEC;
  float ps = 0.f, pd = 0.f;
#pragma unroll
  for (int i = 0; i < VEC; ++i) {
    float hv = row[i];
    ps += hv * asrc[i];
    pd += hv * adst[i];
  }
#pragma unroll
  for (int off = 1; off < 16; off <<= 1) {
    ps += __shfl_xor(ps, off, 64);
    pd += __shfl_xor(pd, off, 64);
  }
  if ((lane & 15) == 0) {
    al_s[node * 4 + head] = ps;
    al_d[node * 4 + head] = pd;
  }
}

__device__ __forceinline__ float4 ldh4(const __half* __restrict__ hg, int src, int lane) {
  float2 gv = *(const float2*)(hg + (size_t)src * 256 + lane * 4);
  float2 a = __half22float2(*(__half2*)&gv.x);
  float2 b = __half22float2(*(__half2*)&gv.y);
  return make_float4(a.x, a.y, b.x, b.y);
}

// ---------------- layer-1 aggregation (4-edge batched online softmax) -------
__global__ __launch_bounds__(256) void gat_agg1(const __half* __restrict__ hg,
                                                const float* __restrict__ als,
                                                const float* __restrict__ aldv,
                                                const int* __restrict__ offs,
                                                const int* __restrict__ csr,
                                                const float* __restrict__ b1,
                                                unsigned short* __restrict__ A2, int Nn) {
  int node = blockIdx.x * 4 + (threadIdx.x >> 6);
  if (node >= Nn) return;
  int lane = threadIdx.x & 63;
  int head = lane >> 4;
  float ald = aldv[node * 4 + head];
  float m = lrelu(als[node * 4 + head] + ald);
  float s = 1.f;  // self-loop: exp(0)
  float4 acc = ldh4(hg, node, lane);
  int beg = offs[node], end = offs[node + 1];
  int k = beg;
  for (; k + 3 < end; k += 4) {
    int s0 = csr[k], s1 = csr[k + 1], s2 = csr[k + 2], s3 = csr[k + 3];
    float e0 = lrelu(als[s0 * 4 + head] + ald);
    float e1 = lrelu(als[s1 * 4 + head] + ald);
    float e2 = lrelu(als[s2 * 4 + head] + ald);
    float e3 = lrelu(als[s3 * 4 + head] + ald);
    float4 h0 = ldh4(hg, s0, lane);
    float4 h1 = ldh4(hg, s1, lane);
    float4 h2 = ldh4(hg, s2, lane);
    float4 h3 = ldh4(hg, s3, lane);
    float m4 = fmaxf(fmaxf(e0, e1), fmaxf(e2, e3));
    float p0 = __expf(e0 - m4), p1 = __expf(e1 - m4);
    float p2 = __expf(e2 - m4), p3 = __expf(e3 - m4);
    float s4 = (p0 + p1) + (p2 + p3);
    float4 a4;
    a4.x = (p0 * h0.x + p1 * h1.x) + (p2 * h2.x + p3 * h3.x);
    a4.y = (p0 * h0.y + p1 * h1.y) + (p2 * h2.y + p3 * h3.y);
    a4.z = (p0 * h0.z + p1 * h1.z) + (p2 * h2.z + p3 * h3.z);
    a4.w = (p0 * h0.w + p1 * h1.w) + (p2 * h2.w + p3 * h3.w);
    float mn = fmaxf(m, m4);
    float sc = __expf(m - mn);
    float qv = __expf(m4 - mn);
    s = s * sc + qv * s4;
    acc.x = acc.x * sc + qv * a4.x;
    acc.y = acc.y * sc + qv * a4.y;
    acc.z = acc.z * sc + qv * a4.z;
    acc.w = acc.w * sc + qv * a4.w;
    m = mn;
  }
  for (; k < end; ++k) {
    int src = csr[k];
    float e = lrelu(als[src * 4 + head] + ald);
    float4 hv = ldh4(hg, src, lane);
    float mn = fmaxf(m, e);
    float sc = __expf(m - mn);
    float p = __expf(e - mn);
    s = s * sc + p;
    acc.x = acc.x * sc + p * hv.x;
    acc.y = acc.y * sc + p * hv.y;
    acc.z = acc.z * sc + p * hv.z;
    acc.w = acc.w * sc + p * hv.w;
    m = mn;
  }
  float inv = 1.f / s;
  const float4 bb = *(const float4*)(b1 + lane * 4);
  float o0 = lrelu(acc.x * inv + bb.x);
  float o1 = lrelu(acc.y * inv + bb.y);
  float o2 = lrelu(acc.z * inv + bb.z);
  float o3 = lrelu(acc.w * inv + bb.w);
  unsigned short h0 = f2bf(o0), h1 = f2bf(o1), h2 = f2bf(o2), h3 = f2bf(o3);
  short4 hv = make_short4((short)h0, (short)h1, (short)h2, (short)h3);
  short4 lv = make_short4((short)f2bf(o0 - bf2f(h0)), (short)f2bf(o1 - bf2f(h1)),
                          (short)f2bf(o2 - bf2f(h2)), (short)f2bf(o3 - bf2f(h3)));
  *(short4*)(A2 + (size_t)node * 512 + lane * 4) = hv;
  *(short4*)(A2 + (size_t)node * 512 + 256 + lane * 4) = lv;
}

// ---------------- layer-2 aggregation (4-edge batched, mean heads + bias) ---
__global__ __launch_bounds__(256) void gat_agg2(const __half* __restrict__ hg,
                                                const float* __restrict__ als,
                                                const float* __restrict__ aldv,
                                                const int* __restrict__ offs,
                                                const int* __restrict__ csr,
                                                const float* __restrict__ b2,
                                                float* __restrict__ out, int Nn) {
  int node = blockIdx.x * 4 + (threadIdx.x >> 6);
  if (node >= Nn) return;
  int lane = threadIdx.x & 63;
  int head = lane >> 4;
  float ald = aldv[node * 4 + head];
  float m = lrelu(als[node * 4 + head] + ald);
  float s = 1.f;
  float2 acc = __half22float2(*(const __half2*)(hg + (size_t)node * 128 + lane * 2));
  int beg = offs[node], end = offs[node + 1];
  int k = beg;
  for (; k + 3 < end; k += 4) {
    int s0 = csr[k], s1 = csr[k + 1], s2 = csr[k + 2], s3 = csr[k + 3];
    float e0 = lrelu(als[s0 * 4 + head] + ald);
    float e1 = lrelu(als[s1 * 4 + head] + ald);
    float e2 = lrelu(als[s2 * 4 + head] + ald);
    float e3 = lrelu(als[s3 * 4 + head] + ald);
    float2 h0 = __half22float2(*(const __half2*)(hg + (size_t)s0 * 128 + lane * 2));
    float2 h1 = __half22float2(*(const __half2*)(hg + (size_t)s1 * 128 + lane * 2));
    float2 h2 = __half22float2(*(const __half2*)(hg + (size_t)s2 * 128 + lane * 2));
    float2 h3 = __half22float2(*(const __half2*)(hg + (size_t)s3 * 128 + lane * 2));
    float m4 = fmaxf(fmaxf(e0, e1), fmaxf(e2, e3));
    float p0 = __expf(e0 - m4), p1 = __expf(e1 - m4);
    float p2 = __expf(e2 - m4), p3 = __expf(e3 - m4);
    float s4 = (p0 + p1) + (p2 + p3);
    float ax = (p0 * h0.x + p1 * h1.x) + (p2 * h2.x + p3 * h3.x);
    float ay = (p0 * h0.y + p1 * h1.y) + (p2 * h2.y + p3 * h3.y);
    float mn = fmaxf(m, m4);
    float sc = __expf(m - mn);
    float qv = __expf(m4 - mn);
    s = s * sc + qv * s4;
    acc.x = acc.x * sc + qv * ax;
    acc.y = acc.y * sc + qv * ay;
    m = mn;
  }
  for (; k < end; ++k) {
    int src = csr[k];
    float e = lrelu(als[src * 4 + head] + ald);
    float2 hv = __half22float2(*(const __half2*)(hg + (size_t)src * 128 + lane * 2));
    float mn = fmaxf(m, e);
    float sc = __expf(m - mn);
    float p = __expf(e - mn);
    s = s * sc + p;
    acc.x = acc.x * sc + p * hv.x;
    acc.y = acc.y * sc + p * hv.y;
    m = mn;
  }
  float inv = 1.f / s;
  float vx = acc.x * inv, vy = acc.y * inv;
  vx += __shfl_xor(vx, 16, 64);
  vx += __shfl_xor(vx, 32, 64);
  vy += __shfl_xor(vy, 16, 64);
  vy += __shfl_xor(vy, 32, 64);
  if (lane < 16) {
    float2 o;
    o.x = vx * 0.25f + b2[lane * 2 + 0];
    o.y = vy * 0.25f + b2[lane * 2 + 1];
    *(float2*)(out + (size_t)node * 32 + lane * 2) = o;
  }
}

extern "C" void kernel_launch(void* const* d_in, const int* in_sizes, int n_in,
                              void* d_out, int out_size, void* d_ws, size_t ws_size,
                              hipStream_t stream) {
  const float* x   = (const float*)d_in[0];
  const int*   ei  = (const int*)d_in[1];
  const float* W1  = (const float*)d_in[2];
  const float* as1 = (const float*)d_in[3];
  const float* ad1 = (const float*)d_in[4];
  const float* b1  = (const float*)d_in[5];
  const float* W2  = (const float*)d_in[6];
  const float* as2 = (const float*)d_in[7];
  const float* ad2 = (const float*)d_in[8];
  const float* b2  = (const float*)d_in[9];
  float* out = (float*)d_out;

  const int CIN = 256, HD1 = 256, HD2 = 128;
  const int Nn = in_sizes[0] / CIN;   // 50000
  const int E  = in_sizes[1] / 2;     // 800000
  const int Mpad = (Nn + 127) & ~127; // 50048
  const int nchunk = (Nn + 255) / 256;  // 196 (fits single-block base scan <=256)

  char* p = (char*)d_ws;
  unsigned short* A12 = (unsigned short*)p; p += (size_t)Mpad * 512 * 2;  // x-split, then hact-split
  float*  hf = (float*)p;  p += (size_t)Nn * 256 * 4;  // h1 fp32, reused as h2 fp32
  __half* hg = (__half*)p; p += (size_t)Nn * 256 * 2;  // h1 fp16, reused as h2 fp16
  unsigned short* Bt1 = (unsigned short*)p; p += (size_t)256 * 768 * 2;
  unsigned short* Bt2 = (unsigned short*)p; p += (size_t)128 * 768 * 2;
  float* als1 = (float*)p; p += (size_t)Nn * 4 * 4;
  float* ald1 = (float*)p; p += (size_t)Nn * 4 * 4;
  float* als2 = (float*)p; p += (size_t)Nn * 4 * 4;
  float* ald2 = (float*)p; p += (size_t)Nn * 4 * 4;
  int* cnt   = (int*)p; p += (size_t)Nn * 4;
  int* offs  = (int*)p; p += (size_t)(Nn + 1) * 4;
  int* cur   = (int*)p; p += (size_t)Nn * 4;
  int* bsum  = (int*)p; p += (size_t)256 * 4;
  int* bbase = (int*)p; p += (size_t)256 * 4;
  int* csr   = (int*)p; p += (size_t)E * 4;

  const int* esrc = ei;
  const int* edst = ei + E;

  // ---- CSR build (hierarchical scan) ----
  hipMemsetAsync(cnt, 0, (size_t)Nn * sizeof(int), stream);
  hist_kernel<<<2048, 256, 0, stream>>>(edst, cnt, E);
  chunk_sum_kernel<<<nchunk, 256, 0, stream>>>(cnt, bsum, Nn);
  scan_base_kernel<<<1, 256, 0, stream>>>(bsum, bbase, offs, nchunk, Nn);
  chunk_scan_kernel<<<nchunk, 256, 0, stream>>>(cnt, bbase, offs, cur, Nn);
  scatter_kernel<<<2048, 256, 0, stream>>>(esrc, edst, cur, csr, E);

  // ---- operand prep ----
  hipMemsetAsync(A12 + (size_t)Nn * 512, 0, (size_t)(Mpad - Nn) * 512 * 2, stream);
  split_x_kernel<<<2048, 256, 0, stream>>>(x, A12, Nn);
  build_bt_kernel<<<256, 256, 0, stream>>>(W1, Bt1, HD1);
  build_bt_kernel<<<128, 256, 0, stream>>>(W2, Bt2, HD2);

  // ---- layer 1 ----
  gemm_split<<<dim3(HD1 / 128, Mpad / 128), 256, 0, stream>>>(A12, Bt1, hf, hg, Nn, HD1);
  compute_al<64, 4><<<(Nn + 3) / 4, 256, 0, stream>>>(hf, as1, ad1, als1, ald1, Nn);
  gat_agg1<<<(Nn + 3) / 4, 256, 0, stream>>>(hg, als1, ald1, offs, csr, b1, A12, Nn);

  // ---- layer 2 ----
  gemm_split<<<dim3(HD2 / 128, Mpad / 128), 256, 0, stream>>>(A12, Bt2, hf, hg, Nn, HD2);
  compute_al<32, 2><<<(Nn + 3) / 4, 256, 0, stream>>>(hf, as2, ad2, als2, ald2, Nn);
  gat_agg2<<<(Nn + 3) / 4, 256, 0, stream>>>(hg, als2, ald2, offs, csr, b2, out, Nn);
}